// Round 1
// baseline (209.908 us; speedup 1.0000x reference)
//
#include <hip/hip_runtime.h>
#include <math.h>

// Dims: B=16, H=64, W=64, Cin=3, F=32, K=3
// conv0 -> relu -> conv_sh -> relu -> conv_sh -> relu -> pool2 ->
// conv_sh -> relu -> conv_sh -> relu -> pool2 -> dense(8192->10) -> softmax

// ---------------- conv0: Cin=3 -> F=32, weights HWIO [3][3][3][32] ----------
__global__ __launch_bounds__(256) void conv0_relu(
    const float* __restrict__ in, const float* __restrict__ W0,
    const float* __restrict__ b0, float* __restrict__ out) {
  __shared__ __align__(16) float w_s[864];  // [tap][c][f] == HWIO layout already
  __shared__ __align__(16) float b_s[32];
  const int tid = threadIdx.x;
  for (int idx = tid; idx < 864; idx += 256) w_s[idx] = W0[idx];
  if (tid < 32) b_s[tid] = b0[tid];
  __syncthreads();

  const int p = blockIdx.x * 256 + tid;  // pixel index in [0, 16*64*64)
  const int b = p >> 12;
  const int rem = p & 4095;
  const int h = rem >> 6;
  const int w = rem & 63;

  float4 acc[8];
#pragma unroll
  for (int i = 0; i < 8; i++) acc[i] = *(const float4*)&b_s[i * 4];

#pragma unroll
  for (int dy = -1; dy <= 1; dy++) {
    const int hh = h + dy;
    const bool vy = (unsigned)hh < 64u;
#pragma unroll
    for (int dx = -1; dx <= 1; dx++) {
      const int ww = w + dx;
      const bool v = vy && ((unsigned)ww < 64u);
      if (!v) continue;
      const int tap = (dy + 1) * 3 + (dx + 1);
      const float* ip = in + (((b << 6) + hh) * 64 + ww) * 3;
      const float c0 = ip[0], c1 = ip[1], c2 = ip[2];
      const float* wp = &w_s[tap * 96];
#pragma unroll
      for (int f4 = 0; f4 < 8; f4++) {
        const float4 w0v = *(const float4*)&wp[f4 * 4];
        const float4 w1v = *(const float4*)&wp[32 + f4 * 4];
        const float4 w2v = *(const float4*)&wp[64 + f4 * 4];
        acc[f4].x += c0 * w0v.x + c1 * w1v.x + c2 * w2v.x;
        acc[f4].y += c0 * w0v.y + c1 * w1v.y + c2 * w2v.y;
        acc[f4].z += c0 * w0v.z + c1 * w1v.z + c2 * w2v.z;
        acc[f4].w += c0 * w0v.w + c1 * w1v.w + c2 * w2v.w;
      }
    }
  }

  float* op = out + p * 32;
#pragma unroll
  for (int f4 = 0; f4 < 8; f4++) {
    float4 r;
    r.x = fmaxf(acc[f4].x, 0.f);
    r.y = fmaxf(acc[f4].y, 0.f);
    r.z = fmaxf(acc[f4].z, 0.f);
    r.w = fmaxf(acc[f4].w, 0.f);
    *(float4*)&op[f4 * 4] = r;
  }
}

// ------------- shared conv: 32 -> 32, w [F=32][tap*32+c], templated H,W -----
template <int H, int W>
__global__ __launch_bounds__(256) void conv_sh_relu(
    const float* __restrict__ in, const float* __restrict__ wsh,
    const float* __restrict__ bsh, float* __restrict__ out) {
  __shared__ __align__(16) float wT[9 * 32 * 32];  // [tap][c][f]
  __shared__ __align__(16) float b_s[32];
  const int tid = threadIdx.x;
  for (int idx = tid; idx < 9216; idx += 256) {
    const int f = idx / 288;
    const int k = idx - f * 288;  // k = tap*32 + c
    wT[k * 32 + f] = wsh[idx];
  }
  if (tid < 32) b_s[tid] = bsh[tid];
  __syncthreads();

  const int p = blockIdx.x * 256 + tid;  // pixel index in [0, 16*H*W)
  const int b = p / (H * W);
  const int rem = p - b * (H * W);
  const int h = rem / W;
  const int w = rem - h * W;

  float4 acc[8];
#pragma unroll
  for (int i = 0; i < 8; i++) acc[i] = *(const float4*)&b_s[i * 4];

#pragma unroll
  for (int dy = -1; dy <= 1; dy++) {
    const int hh = h + dy;
    const bool vy = (unsigned)hh < (unsigned)H;
#pragma unroll
    for (int dx = -1; dx <= 1; dx++) {
      const int ww = w + dx;
      if (!(vy && ((unsigned)ww < (unsigned)W))) continue;
      const int tap = (dy + 1) * 3 + (dx + 1);
      const float* ip = in + (((b * H) + hh) * W + ww) * 32;
      const float* wp = &wT[tap * 1024];
#pragma unroll
      for (int c4 = 0; c4 < 8; c4++) {
        const float4 iv = *(const float4*)&ip[c4 * 4];
#pragma unroll
        for (int cc = 0; cc < 4; cc++) {
          const float ival = cc == 0 ? iv.x : cc == 1 ? iv.y : cc == 2 ? iv.z : iv.w;
          const float* wrow = wp + (c4 * 4 + cc) * 32;
#pragma unroll
          for (int f4 = 0; f4 < 8; f4++) {
            const float4 wv = *(const float4*)&wrow[f4 * 4];
            acc[f4].x += ival * wv.x;
            acc[f4].y += ival * wv.y;
            acc[f4].z += ival * wv.z;
            acc[f4].w += ival * wv.w;
          }
        }
      }
    }
  }

  float* op = out + p * 32;
#pragma unroll
  for (int f4 = 0; f4 < 8; f4++) {
    float4 r;
    r.x = fmaxf(acc[f4].x, 0.f);
    r.y = fmaxf(acc[f4].y, 0.f);
    r.z = fmaxf(acc[f4].z, 0.f);
    r.w = fmaxf(acc[f4].w, 0.f);
    *(float4*)&op[f4 * 4] = r;
  }
}

// ---------------- 2x2 maxpool stride 2, NHWC, C=32 --------------------------
template <int HO, int WO, int LGW, int LGH>
__global__ __launch_bounds__(256) void maxpool2(const float* __restrict__ in,
                                                float* __restrict__ out) {
  const int idx = blockIdx.x * 256 + threadIdx.x;  // float4 index
  const int f4 = idx & 7;
  const int r = idx >> 3;
  const int wo = r & (WO - 1);
  const int r2 = r >> LGW;
  const int ho = r2 & (HO - 1);
  const int b = r2 >> LGH;
  const int Win = WO * 2;
  const float* p00 = in + (((b * 2 * HO + 2 * ho) * Win) + 2 * wo) * 32 + f4 * 4;
  const float4 a = *(const float4*)p00;
  const float4 bb = *(const float4*)(p00 + 32);
  const float4 c = *(const float4*)(p00 + Win * 32);
  const float4 d = *(const float4*)(p00 + Win * 32 + 32);
  float4 m;
  m.x = fmaxf(fmaxf(a.x, bb.x), fmaxf(c.x, d.x));
  m.y = fmaxf(fmaxf(a.y, bb.y), fmaxf(c.y, d.y));
  m.z = fmaxf(fmaxf(a.z, bb.z), fmaxf(c.z, d.z));
  m.w = fmaxf(fmaxf(a.w, bb.w), fmaxf(c.w, d.w));
  *(float4*)(out + ((b * HO + ho) * WO + wo) * 32 + f4 * 4) = m;
}

// ---------------- dense 8192->10 + softmax, one block per batch row ---------
__global__ __launch_bounds__(256) void dense_softmax(
    const float* __restrict__ x, const float* __restrict__ Wd,
    const float* __restrict__ bd, float* __restrict__ out) {
  const int b = blockIdx.x;
  const int tid = threadIdx.x;
  const float* xb = x + b * 8192;
  float acc[10];
#pragma unroll
  for (int j = 0; j < 10; j++) acc[j] = 0.f;
  for (int i = tid; i < 8192; i += 256) {
    const float xv = xb[i];
    const float* wr = Wd + i * 10;
#pragma unroll
    for (int j = 0; j < 10; j++) acc[j] += xv * wr[j];
  }
  __shared__ float red[10 * 256];
#pragma unroll
  for (int j = 0; j < 10; j++) red[j * 256 + tid] = acc[j];
  __syncthreads();
  for (int s = 128; s > 0; s >>= 1) {
    if (tid < s) {
#pragma unroll
      for (int j = 0; j < 10; j++) red[j * 256 + tid] += red[j * 256 + tid + s];
    }
    __syncthreads();
  }
  if (tid == 0) {
    float lg[10];
    float m = -1e30f;
#pragma unroll
    for (int j = 0; j < 10; j++) {
      lg[j] = red[j * 256] + bd[j];
      m = fmaxf(m, lg[j]);
    }
    float s = 0.f;
#pragma unroll
    for (int j = 0; j < 10; j++) {
      lg[j] = expf(lg[j] - m);
      s += lg[j];
    }
    const float inv = 1.f / s;
#pragma unroll
    for (int j = 0; j < 10; j++) out[b * 10 + j] = lg[j] * inv;
  }
}

extern "C" void kernel_launch(void* const* d_in, const int* in_sizes, int n_in,
                              void* d_out, int out_size, void* d_ws, size_t ws_size,
                              hipStream_t stream) {
  const float* in = (const float*)d_in[0];
  const float* W0 = (const float*)d_in[1];
  const float* b0 = (const float*)d_in[2];
  const float* wsh = (const float*)d_in[3];
  const float* bsh = (const float*)d_in[4];
  const float* Wd = (const float*)d_in[5];
  const float* bd = (const float*)d_in[6];
  float* out = (float*)d_out;

  float* A = (float*)d_ws;                 // 16*64*64*32 = 2,097,152 floats (8 MB)
  float* B = A + 16 * 64 * 64 * 32;        // second 8 MB buffer

  conv0_relu<<<256, 256, 0, stream>>>(in, W0, b0, A);
  conv_sh_relu<64, 64><<<256, 256, 0, stream>>>(A, wsh, bsh, B);
  conv_sh_relu<64, 64><<<256, 256, 0, stream>>>(B, wsh, bsh, A);
  maxpool2<32, 32, 5, 5><<<512, 256, 0, stream>>>(A, B);   // 64x64 -> 32x32
  conv_sh_relu<32, 32><<<64, 256, 0, stream>>>(B, wsh, bsh, A);
  conv_sh_relu<32, 32><<<64, 256, 0, stream>>>(A, wsh, bsh, B);
  maxpool2<16, 16, 4, 4><<<128, 256, 0, stream>>>(B, A);   // 32x32 -> 16x16
  dense_softmax<<<16, 256, 0, stream>>>(A, Wd, bd, out);
}